// Round 5
// baseline (185.501 us; speedup 1.0000x reference)
//
#include <hip/hip_runtime.h>

// 3x3 median blur + residual, zero padding, x:(8,3,1024,1024) f32.
// Async-LDS ring pipeline (R4) + conflict-free halos (shfl off the b128
// instead of 8-way-conflicted ds_read_b32) + XCD-aware plane swizzle
// (3 planes per XCD so strip-boundary re-reads hit the local 4MB L2).

typedef float v4f __attribute__((ext_vector_type(4)));

#define S2(a,b) { float _t=fminf(a,b); (b)=fmaxf(a,b); (a)=_t; }
__device__ __forceinline__ float med3f(float a,float b,float c){
    return fmaxf(fminf(a,b), fminf(fmaxf(a,b),c));
}

constexpr int W = 1024, H = 1024;
constexpr int ROWS = 16;   // output rows per block
constexpr int NBUF = 6;    // LDS row ring (pipeline depth 5 + 1)

__global__ __launch_bounds__(256) void median_blur_kernel(
    const float* __restrict__ xin, float* __restrict__ out)
{
    __shared__ float smem[NBUF * W];           // 24 KB -> 6 blocks/CU
    const int tx   = threadIdx.x;
    const int lane = tx & 63;
    const int x0   = tx << 2;                  // 4 px per thread

    // XCD-aware swizzle: consecutive blockIdx round-robin the 8 XCDs, so
    // give block b -> xcd = b&7 a plane from that XCD's private set of 3.
    const int b     = blockIdx.x;              // 0..1535
    const int xcd   = b & 7;
    const int i     = b >> 3;                  // 0..191
    const int plane = xcd * 3 + (i % 3);       // 24 planes, 3 per XCD
    const int y0    = (i / 3) * ROWS;          // strip 0..63

    const float* base  = xin + (size_t)plane * H * W;
    float*       obase = out + (size_t)plane * H * W;

    // stage s holds image row y0-1+s (clamped; clamped rows' content unused)
    auto issue = [&](int s) {
        int y = y0 - 1 + s;
        y = y < 0 ? 0 : (y > H - 1 ? H - 1 : y);
        const float* g = base + (size_t)y * W + x0;
        float* l = &smem[(s % NBUF) * W + x0];
        __builtin_amdgcn_global_load_lds(
            (const __attribute__((address_space(1))) void*)g,
            (__attribute__((address_space(3))) void*)l, 16, 0, 0);
    };

    issue(0); issue(1); issue(2); issue(3); issue(4);   // 5 stages in flight

    // read a staged row: b128 + shfl halos (conflict-free); only lanes 0/63
    // touch LDS scalars (4 lanes/block divergent), edges padded with zero.
    auto readrow = [&](int s, bool valid, float* d) {
        if (valid) {                            // block-uniform branch
            const float* sm = &smem[(s % NBUF) * W];
            v4f c = *reinterpret_cast<const v4f*>(sm + x0);
            float l = __shfl_up(c.w, 1);
            float r = __shfl_down(c.x, 1);
            if (lane == 0)  l = (x0 > 0)     ? sm[x0 - 1] : 0.0f;
            if (lane == 63) r = (x0 + 4 < W) ? sm[x0 + 4] : 0.0f;
            d[0] = l;
            d[1] = c.x; d[2] = c.y; d[3] = c.z; d[4] = c.w;
            d[5] = r;
        } else {
#pragma unroll
            for (int j = 0; j < 6; ++j) d[j] = 0.0f;
        }
    };

    auto compute_store = [&](int r, const float* t, const float* m, const float* bb) {
        float lo[6], mi[6], hi[6];
#pragma unroll
        for (int j = 0; j < 6; ++j) {           // vertical sort of 6 columns
            float a = t[j], c0 = m[j], d = bb[j];
            S2(a, c0); S2(c0, d); S2(a, c0);
            lo[j] = a; mi[j] = c0; hi[j] = d;
        }
        v4f o;
#pragma unroll
        for (int j = 0; j < 4; ++j) {
            float mxlo = fmaxf(lo[j], fmaxf(lo[j + 1], lo[j + 2]));
            float mnhi = fminf(hi[j], fminf(hi[j + 1], hi[j + 2]));
            float mdmi = med3f(mi[j], mi[j + 1], mi[j + 2]);
            float med  = med3f(mxlo, mdmi, mnhi);
            float xc   = m[j + 1];
            o[j] = xc + 0.2f * (med - xc);
        }
        __builtin_nontemporal_store(o, (v4f*)(obase + (size_t)(y0 + r) * W + x0));
    };

    // iter r: wait until stage r+2 landed (vmcnt<=VM), barrier, consume
    // stages r..r+2, issue stage r+5 (its buffer was last read at iter r-1,
    // protected by this barrier), compute+store. Manual waitcnt + raw
    // s_barrier avoids __syncthreads' full vmcnt(0) drain.
#define ITER(R, VM) {                                                   \
    asm volatile("" ::: "memory");                                      \
    __builtin_amdgcn_s_waitcnt(0xF70 | (VM));                           \
    __builtin_amdgcn_s_barrier();                                       \
    asm volatile("" ::: "memory");                                      \
    float t[6], mm[6], bb[6];                                           \
    readrow((R),     y0 + (R) - 1 >= 0, t);                             \
    readrow((R) + 1, true,              mm);                            \
    readrow((R) + 2, y0 + (R) + 1 < H,  bb);                            \
    if ((R) + 5 <= ROWS + 1) issue((R) + 5);                            \
    compute_store((R), t, mm, bb);                                      \
}

    ITER(0, 2)  ITER(1, 2)  ITER(2, 2)  ITER(3, 2)
    ITER(4, 2)  ITER(5, 2)  ITER(6, 2)  ITER(7, 2)
    ITER(8, 2)  ITER(9, 2)  ITER(10, 2) ITER(11, 2)
    ITER(12, 2) ITER(13, 2) ITER(14, 1) ITER(15, 0)
#undef ITER
}

extern "C" void kernel_launch(void* const* d_in, const int* in_sizes, int n_in,
                              void* d_out, int out_size, void* d_ws, size_t ws_size,
                              hipStream_t stream) {
    const float* x = (const float*)d_in[0];
    float* out = (float*)d_out;
    const int planes = in_sizes[0] / (H * W);   // 24
    dim3 block(256);
    dim3 grid((H / ROWS) * planes);             // 1536 blocks, linear for swizzle
    median_blur_kernel<<<grid, block, 0, stream>>>(x, out);
}

// Round 6
// 176.005 us; speedup vs baseline: 1.0539x; 1.0539x over previous
//
#include <hip/hip_runtime.h>

// 3x3 median blur + residual, zero padding, x:(8,3,1024,1024) f32.
// Flat-burst MLP kernel: each block = 8 output rows x 1024 px. All 10 row
// loads issued as independent dwordx4 up front and PINNED RESIDENT via empty
// asm reg-ties (defeats the compiler's load-sinking that serialized R1-R5;
// VGPR_Count 16..40 in all prior rounds = ~zero memory-level parallelism).
// Halos: intra-wave shfl + 320B LDS exchange for wave-boundary columns.

typedef float v4f __attribute__((ext_vector_type(4)));

#define S2(a,b) { float _t=fminf(a,b); (b)=fmaxf(a,b); (a)=_t; }
__device__ __forceinline__ float med3f(float a,float b,float c){
    return fmaxf(fminf(a,b), fminf(fmaxf(a,b),c));
}

constexpr int W = 1024, H = 1024;
constexpr int R = 8;              // output rows per block
constexpr int NL = R + 2;         // loaded rows per block (10)

__global__ __launch_bounds__(256, 2) void median_blur_kernel(
    const float* __restrict__ xin, float* __restrict__ out)
{
    __shared__ float eL[NL][4];   // per row, per wave: c.x of lane 0  (px 256w)
    __shared__ float eR[NL][4];   // per row, per wave: c.w of lane 63 (px 256w+255)

    const int tx   = threadIdx.x;
    const int lane = tx & 63;
    const int wv   = tx >> 6;                 // wave 0..3
    const int x0   = tx << 2;                 // 4 px per thread, covers full row
    const int y0   = blockIdx.x * R;
    const size_t plane = (size_t)blockIdx.y * H * W;
    const float* base  = xin + plane;
    float*       obase = out + plane;

    // ---- burst: 10 independent coalesced dwordx4 loads, no deps between them
    v4f row[NL];
#pragma unroll
    for (int s = 0; s < NL; ++s) {
        int y = y0 - 1 + s;
        y = y < 0 ? 0 : (y > H - 1 ? H - 1 : y);   // clamped addr; zeroed at use
        row[s] = *reinterpret_cast<const v4f*>(base + (size_t)y * W + x0);
    }
    // pin every loaded component in a VGPR: compiler cannot sink/serialize
    {
        float* rf = reinterpret_cast<float*>(row);
#pragma unroll
        for (int i = 0; i < NL * 4; ++i) asm volatile("" : "+v"(rf[i]));
    }

    // ---- wave-boundary column exchange (lanes 0/63 only; 320 B LDS)
    if (lane == 0) {
#pragma unroll
        for (int s = 0; s < NL; ++s) eL[s][wv] = row[s].x;
    }
    if (lane == 63) {
#pragma unroll
        for (int s = 0; s < NL; ++s) eR[s][wv] = row[s].w;
    }
    __syncthreads();

    // ---- expand each loaded row to 6-wide (halos via shfl + LDS), zero-pad y
    float rr[NL][6];
#pragma unroll
    for (int s = 0; s < NL; ++s) {
        const int y = y0 - 1 + s;
        const bool valid = (y >= 0) && (y < H);    // block-uniform
        v4f c = row[s];
        float l = __shfl_up(c.w, 1);
        float r = __shfl_down(c.x, 1);
        if (lane == 0)  l = (wv > 0) ? eR[s][wv - 1] : 0.0f;  // image edge -> 0
        if (lane == 63) r = (wv < 3) ? eL[s][wv + 1] : 0.0f;
        rr[s][0] = valid ? l   : 0.0f;
        rr[s][1] = valid ? c.x : 0.0f;
        rr[s][2] = valid ? c.y : 0.0f;
        rr[s][3] = valid ? c.z : 0.0f;
        rr[s][4] = valid ? c.w : 0.0f;
        rr[s][5] = valid ? r   : 0.0f;
    }

    // ---- 8 output rows: column sort3 + med3-of-candidates, store immediately
#pragma unroll
    for (int r = 0; r < R; ++r) {
        const float* t  = rr[r];
        const float* mm = rr[r + 1];
        const float* bb = rr[r + 2];
        float lo[6], mi[6], hi[6];
#pragma unroll
        for (int j = 0; j < 6; ++j) {
            float a = t[j], c0 = mm[j], d = bb[j];
            S2(a, c0); S2(c0, d); S2(a, c0);
            lo[j] = a; mi[j] = c0; hi[j] = d;
        }
        v4f o;
#pragma unroll
        for (int j = 0; j < 4; ++j) {
            float mxlo = fmaxf(lo[j], fmaxf(lo[j + 1], lo[j + 2]));
            float mnhi = fminf(hi[j], fminf(hi[j + 1], hi[j + 2]));
            float mdmi = med3f(mi[j], mi[j + 1], mi[j + 2]);
            float med  = med3f(mxlo, mdmi, mnhi);
            float xc   = mm[j + 1];
            o[j] = xc + 0.2f * (med - xc);
        }
        __builtin_nontemporal_store(o,
            reinterpret_cast<v4f*>(obase + (size_t)(y0 + r) * W + x0));
    }
}

extern "C" void kernel_launch(void* const* d_in, const int* in_sizes, int n_in,
                              void* d_out, int out_size, void* d_ws, size_t ws_size,
                              hipStream_t stream) {
    const float* x = (const float*)d_in[0];
    float* out = (float*)d_out;
    const int planes = in_sizes[0] / (H * W);   // 24
    dim3 block(256);
    dim3 grid(H / R, planes);                   // 128 x 24 = 3072 blocks
    median_blur_kernel<<<grid, block, 0, stream>>>(x, out);
}